// Round 1
// 602.836 us; speedup vs baseline: 1.2220x; 1.2220x over previous
//
#include <hip/hip_runtime.h>
#include <math.h>

// B=64 T=50 V=32000 E=64 DH=128 H=8 M=256 ; rows R = B*T = 3200
#define T_ 50
#define R_ 3200

using u16 = unsigned short;
typedef __attribute__((ext_vector_type(8))) __bf16 bf16x8;
typedef __attribute__((ext_vector_type(4))) float f32x4;

__device__ __forceinline__ float bf2f(u16 u) {
  union { unsigned int i; float f; } x; x.i = ((unsigned int)u) << 16; return x.f;
}
__device__ __forceinline__ u16 f2bf(float f) {
  union { float f; unsigned int i; } x; x.f = f;
  unsigned int r = x.i + 0x7FFFu + ((x.i >> 16) & 1u);  // RNE
  return (u16)(r >> 16);
}
__device__ __forceinline__ void split2(float v, u16& hi, u16& lo) {
  hi = f2bf(v);
  lo = f2bf(v - bf2f(hi));
}
__device__ __forceinline__ float gelu_f(float v) {
  return 0.5f * v * (1.0f + erff(v * 0.70710678118654752f));
}

// ---------------- fused prep: embed(split) + weight pack + Wf transpose -----
// blocks [0,800): h split ; [800,1964): pack ; [1964,2464): Wf transpose
__global__ __launch_bounds__(256) void k_prep(
    const int* __restrict__ x, const float* __restrict__ tok, const float* __restrict__ pos,
    const float* __restrict__ Wq, const float* __restrict__ Wk, const float* __restrict__ Wv,
    const float* __restrict__ bq, const float* __restrict__ bk, const float* __restrict__ bv,
    const float* __restrict__ Wo, const float* __restrict__ W1, const float* __restrict__ W2,
    const float* __restrict__ Wf,
    u16* __restrict__ hH, u16* __restrict__ hL,
    u16* __restrict__ WqkvTh, u16* __restrict__ WqkvTl, float* __restrict__ bqkv,
    u16* __restrict__ WoTh, u16* __restrict__ WoTl,
    u16* __restrict__ W1Th, u16* __restrict__ W1Tl,
    u16* __restrict__ W2Th, u16* __restrict__ W2Tl,
    u16* __restrict__ WfTh, u16* __restrict__ WfTl) {
  __shared__ __align__(16) float tile[64][68];
  int bid = blockIdx.x;
  if (bid < 800) {  // embed + split: h[row][e] = tok[x[row]][e] + pos[t][e]
    int i = bid * 256 + threadIdx.x;
    int row = i >> 6, e = i & 63;
    int t = row % T_;
    int v = x[row];
    split2(tok[(long)v * 64 + e] + pos[t * 64 + e], hH[i], hL[i]);
    return;
  }
  if (bid < 1964) {  // pack weights into split-bf16 B^T layouts
    int i = (bid - 800) * 256 + threadIdx.x;
    const int S0 = 196608, S1 = 3072, S2 = 65536, S3 = 16384;
    if (i < S0) {  // WqkvT[n][e] = W_p[head][e][d] ; n = p*1024 + head*128 + d
      int n = i >> 6, e = i & 63;
      int p = n >> 10, rem = n & 1023;
      int hh_ = rem >> 7, d = rem & 127;
      const float* W = (p == 0) ? Wq : ((p == 1) ? Wk : Wv);
      split2(W[hh_ * 8192 + e * 128 + d], WqkvTh[i], WqkvTl[i]);
      return;
    }
    i -= S0;
    if (i < S1) { int p = i >> 10, rem = i & 1023;
      const float* bb = (p == 0) ? bq : ((p == 1) ? bk : bv);
      bqkv[i] = bb[rem]; return; }
    i -= S1;
    if (i < S2) { int n = i >> 10, k = i & 1023;
      split2(Wo[k * 64 + n], WoTh[i], WoTl[i]); return; }
    i -= S2;
    if (i < S3) { int n = i >> 6, k = i & 63;
      split2(W1[k * 256 + n], W1Th[i], W1Tl[i]); return; }
    i -= S3;
    { int n = i >> 8, k = i & 255;
      split2(W2[k * 64 + n], W2Th[i], W2Tl[i]); }
    return;
  }
  // Wf [64][32000] f32 -> WfT hi/lo bf16 [32000][64]
  int n0 = (bid - 1964) * 64;
  for (int c = threadIdx.x; c < 1024; c += 256) {
    int k = c >> 4, ch = (c & 15) * 4;
    *(float4*)&tile[k][ch] = *(const float4*)&Wf[(long)k * 32000 + n0 + ch];
  }
  __syncthreads();
  for (int c = threadIdx.x; c < 1024; c += 256) {
    int n = c >> 4, ch = (c & 15) * 4;
    u16 th[4], tl[4];
#pragma unroll
    for (int j = 0; j < 4; ++j) split2(tile[ch + j][n], th[j], tl[j]);
    *(ushort4*)&WfTh[(long)(n0 + n) * 64 + ch] = *(ushort4*)th;
    *(ushort4*)&WfTl[(long)(n0 + n) * 64 + ch] = *(ushort4*)tl;
  }
}

// ---------------- attention: one block per (b,head), fp32, lane=s layout ----
// QKV f32 [3200][3072]: cols [0,1024)=Q, [1024,2048)=K, [2048,3072)=V
// Output written pre-split (hi/lo bf16) — sole consumer is the Wo GEMM.
__global__ __launch_bounds__(256) void k_attn(const float* __restrict__ QKV,
                                              u16* __restrict__ Oh,
                                              u16* __restrict__ Ol) {
  int bh = blockIdx.x;
  int b = bh >> 3, hd = bh & 7;
  // Kl padded to 133 floats: bank = (133*s + d) % 32 = (5s + d) % 32 ->
  // lane-indexed row reads Kl[lane][d] are conflict-free (2-way at worst).
  __shared__ __align__(16) float Kl[64][133];
  __shared__ __align__(16) float Vl[T_][128];
  __shared__ float Qw[4][128];
  __shared__ float Pw[4][64];
  const int tid = threadIdx.x, lane = tid & 63, wave = tid >> 6;
  const float* base = QKV + (long)b * T_ * 3072 + hd * 128;
  for (int c = tid; c < T_ * 32; c += 256) {
    int s = c >> 5, c4 = (c & 31) * 4;
    float4 kv = *(const float4*)&base[(long)s * 3072 + 1024 + c4];
    Kl[s][c4] = kv.x; Kl[s][c4 + 1] = kv.y; Kl[s][c4 + 2] = kv.z; Kl[s][c4 + 3] = kv.w;
    *(float4*)&Vl[s][c4] = *(const float4*)&base[(long)s * 3072 + 2048 + c4];
  }
  for (int c = tid; c < 14 * 32; c += 256) {  // zero pad rows 50..63
    int s = 50 + (c >> 5), c4 = (c & 31) * 4;
    Kl[s][c4] = 0.f; Kl[s][c4 + 1] = 0.f; Kl[s][c4 + 2] = 0.f; Kl[s][c4 + 3] = 0.f;
  }
  __syncthreads();
  const float scale = 0.0883883476483184406f;  // 1/sqrt(128)
  for (int r = wave; r < T_; r += 4) {
    // broadcast q row via per-wave LDS (intra-wave RAW: compiler lgkmcnt)
    Qw[wave][lane] = base[(long)r * 3072 + lane];
    Qw[wave][64 + lane] = base[(long)r * 3072 + 64 + lane];
    // scores: lane owns s = lane ; straight FMA chain over d, no shuffles
    float p = 0.f;
#pragma unroll 8
    for (int d = 0; d < 128; ++d) p += Qw[wave][d] * Kl[lane][d];
    float sc = (lane <= r) ? p * scale : -INFINITY;
    float mx = sc;
    mx = fmaxf(mx, __shfl_xor(mx, 32)); mx = fmaxf(mx, __shfl_xor(mx, 16));
    mx = fmaxf(mx, __shfl_xor(mx, 8));  mx = fmaxf(mx, __shfl_xor(mx, 4));
    mx = fmaxf(mx, __shfl_xor(mx, 2));  mx = fmaxf(mx, __shfl_xor(mx, 1));
    float e = expf(sc - mx);  // masked lanes: exp(-inf) = 0
    float sum = e;
    sum += __shfl_xor(sum, 32); sum += __shfl_xor(sum, 16); sum += __shfl_xor(sum, 8);
    sum += __shfl_xor(sum, 4);  sum += __shfl_xor(sum, 2);  sum += __shfl_xor(sum, 1);
    Pw[wave][lane] = e / sum;
    float o0 = 0.f, o1 = 0.f;
#pragma unroll 4
    for (int s = 0; s <= r; ++s) {
      float pv = Pw[wave][s];       // LDS broadcast (uniform addr, free)
      o0 += pv * Vl[s][lane];       // 2-way bank alias = free
      o1 += pv * Vl[s][64 + lane];
    }
    long orow = ((long)b * T_ + r) * 1024 + hd * 128;
    u16 hi, lo;
    split2(o0, hi, lo); Oh[orow + lane] = hi;      Ol[orow + lane] = lo;
    split2(o1, hi, lo); Oh[orow + 64 + lane] = hi; Ol[orow + 64 + lane] = lo;
  }
}

// ------- split-precision MFMA GEMM: C = A @ Bt^T + bias ---------------------
// A pre-split bf16 hi/lo [M][K] in global (rows per-wave exclusive -> A-frags
// loaded DIRECTLY from global, L2-hot; no A-LDS, no A staging barrier).
// Bt pre-split bf16 hi/lo [N][K] staged in LDS (+8 u16 pad).
// D = ah*bh + al*bh + ah*bl  (al*bl ~ 2^-18 rel, dropped).
// 16x16x32 MFMA verified layouts: A[m=lane&15][k=quad*8+j];
// C/D: col=lane&15, row=quad*4+reg.
// BM=64, 4 waves: wave w owns rows [16w,16w+16), all BN cols in 16-wide tiles.
template <int BN, int BK, int ACT, int OSPLIT>
__global__ __launch_bounds__(256) void k_gemm(
    const u16* __restrict__ Ah, const u16* __restrict__ Al,
    const u16* __restrict__ Bth, const u16* __restrict__ Btl,
    const float* __restrict__ bias,
    float* __restrict__ C, u16* __restrict__ Ch, u16* __restrict__ Cl,
    int ldc, int K) {
  constexpr int BM = 64;
  constexpr int TN = BN / 16;
  constexpr int BKW = BK / 8;
  __shared__ __align__(16) u16 Bh[BN][BK + 8];
  __shared__ __align__(16) u16 Bl[BN][BK + 8];
  const int m0 = blockIdx.x * BM, n0 = blockIdx.y * BN;
  const int tid = threadIdx.x, lane = tid & 63, wave = tid >> 6;
  const int ln = lane & 15, quad = lane >> 4;
  const long arow = (long)(m0 + wave * 16 + ln) * K;
  f32x4 acc[TN];
#pragma unroll
  for (int tn = 0; tn < TN; ++tn)
#pragma unroll
    for (int i = 0; i < 4; ++i) acc[tn][i] = 0.f;

  for (int kk = 0; kk < K; kk += BK) {
#pragma unroll
    for (int c0 = 0; c0 < BN * BKW; c0 += 256) {
      int c = c0 + tid;
      int r = c / BKW, c8 = (c % BKW) * 8;
      *(uint4*)&Bh[r][c8] = *(const uint4*)&Bth[(long)(n0 + r) * K + kk + c8];
      *(uint4*)&Bl[r][c8] = *(const uint4*)&Btl[(long)(n0 + r) * K + kk + c8];
    }
    __syncthreads();
#pragma unroll
    for (int ks = 0; ks < BK / 32; ++ks) {
      bf16x8 a_h = *(const bf16x8*)&Ah[arow + kk + ks * 32 + quad * 8];
      bf16x8 a_l = *(const bf16x8*)&Al[arow + kk + ks * 32 + quad * 8];
#pragma unroll
      for (int tn = 0; tn < TN; ++tn) {
        bf16x8 b_h = *(const bf16x8*)&Bh[tn * 16 + ln][ks * 32 + quad * 8];
        bf16x8 b_l = *(const bf16x8*)&Bl[tn * 16 + ln][ks * 32 + quad * 8];
        acc[tn] = __builtin_amdgcn_mfma_f32_16x16x32_bf16(a_h, b_h, acc[tn], 0, 0, 0);
        acc[tn] = __builtin_amdgcn_mfma_f32_16x16x32_bf16(a_l, b_h, acc[tn], 0, 0, 0);
        acc[tn] = __builtin_amdgcn_mfma_f32_16x16x32_bf16(a_h, b_l, acc[tn], 0, 0, 0);
      }
    }
    __syncthreads();
  }
#pragma unroll
  for (int tn = 0; tn < TN; ++tn) {
    int col = n0 + tn * 16 + ln;
    float bv = bias[col];
#pragma unroll
    for (int rr = 0; rr < 4; ++rr) {
      float v = acc[tn][rr] + bv;
      if (ACT) v = gelu_f(v);
      long idx = (long)(m0 + wave * 16 + quad * 4 + rr) * ldc + col;
      if constexpr (OSPLIT) {
        u16 hi, lo; split2(v, hi, lo);
        Ch[idx] = hi; Cl[idx] = lo;
      } else {
        C[idx] = v;
      }
    }
  }
}

extern "C" void kernel_launch(void* const* d_in, const int* in_sizes, int n_in,
                              void* d_out, int out_size, void* d_ws, size_t ws_size,
                              hipStream_t stream) {
  const int*   x   = (const int*)d_in[0];
  const float* tok = (const float*)d_in[1];
  const float* pos = (const float*)d_in[2];
  const float* Wq  = (const float*)d_in[3];
  const float* bq  = (const float*)d_in[4];
  const float* Wk  = (const float*)d_in[5];
  const float* bk  = (const float*)d_in[6];
  const float* Wv  = (const float*)d_in[7];
  const float* bv  = (const float*)d_in[8];
  const float* Wo  = (const float*)d_in[9];
  const float* bo  = (const float*)d_in[10];
  const float* W1  = (const float*)d_in[11];
  const float* b1  = (const float*)d_in[12];
  const float* W2  = (const float*)d_in[13];
  const float* b2  = (const float*)d_in[14];
  const float* Wf  = (const float*)d_in[15];
  const float* bfv = (const float*)d_in[16];

  char* ws = (char*)d_ws;
  u16*   hH     = (u16*)(ws + 0);            // 3200*64 u16
  u16*   hL     = (u16*)(ws + 409600);
  float* QKV    = (float*)(ws + 819200);     // 3200*3072 f32
  u16*   oH     = (u16*)(ws + 40140800);     // 3200*1024 u16
  u16*   oL     = (u16*)(ws + 46694400);
  u16*   aH     = (u16*)(ws + 53248000);     // 3200*64 u16
  u16*   aL     = (u16*)(ws + 53657600);
  u16*   mH     = (u16*)(ws + 54067200);     // 3200*256 u16
  u16*   mL     = (u16*)(ws + 55705600);
  u16*   yH     = (u16*)(ws + 57344000);     // 3200*64 u16
  u16*   yL     = (u16*)(ws + 57753600);
  u16*   WqkvTh = (u16*)(ws + 58163200);     // 3072*64
  u16*   WqkvTl = (u16*)(ws + 58556416);
  float* bqkv   = (float*)(ws + 58949632);   // 3072 f32
  u16*   WoTh   = (u16*)(ws + 58961920);     // 64*1024
  u16*   WoTl   = (u16*)(ws + 59092992);
  u16*   W1Th   = (u16*)(ws + 59224064);     // 256*64
  u16*   W1Tl   = (u16*)(ws + 59256832);
  u16*   W2Th   = (u16*)(ws + 59289600);     // 64*256
  u16*   W2Tl   = (u16*)(ws + 59322368);
  u16*   WfTh   = (u16*)(ws + 59355136);     // 32000*64
  u16*   WfTl   = (u16*)(ws + 63451136);     // end 67,547,136
  float* out    = (float*)d_out;

  k_prep<<<dim3(2464), 256, 0, stream>>>(x, tok, pos, Wq, Wk, Wv, bq, bk, bv,
      Wo, W1, W2, Wf, hH, hL, WqkvTh, WqkvTl, bqkv, WoTh, WoTl,
      W1Th, W1Tl, W2Th, W2Tl, WfTh, WfTl);
  // QKV: [3200,64] @ [64,3072] -> f32
  k_gemm<128, 64, 0, 0><<<dim3(50, 24), 256, 0, stream>>>(
      hH, hL, WqkvTh, WqkvTl, bqkv, QKV, nullptr, nullptr, 3072, 64);
  k_attn<<<dim3(512), 256, 0, stream>>>(QKV, oH, oL);
  // Wo: [3200,1024] @ [1024,64] -> split a
  k_gemm<64, 256, 0, 1><<<dim3(50, 1), 256, 0, stream>>>(
      oH, oL, WoTh, WoTl, bo, nullptr, aH, aL, 64, 1024);
  // FFN1 + exact GELU: [3200,64] @ [64,256] -> split m
  k_gemm<128, 64, 1, 1><<<dim3(50, 2), 256, 0, stream>>>(
      aH, aL, W1Th, W1Tl, b1, nullptr, mH, mL, 256, 64);
  // FFN2: [3200,256] @ [256,64] -> split y
  k_gemm<64, 256, 0, 1><<<dim3(50, 1), 256, 0, stream>>>(
      mH, mL, W2Th, W2Tl, b2, nullptr, yH, yL, 64, 256);
  // Final: [3200,64] @ [64,32000] -> logits f32 (write-bound, ~410 MB)
  k_gemm<128, 64, 0, 0><<<dim3(50, 250), 256, 0, stream>>>(
      yH, yL, WfTh, WfTl, bfv, out, nullptr, nullptr, 32000, 64);
}